// Round 4
// baseline (447.247 us; speedup 1.0000x reference)
//
#include <hip/hip_runtime.h>
#include <hip/hip_bf16.h>
#include <math.h>

typedef __bf16 bf16_t;
typedef __attribute__((ext_vector_type(4))) __bf16 bf16x4;
typedef __attribute__((ext_vector_type(8))) __bf16 bf16x8;
typedef __attribute__((ext_vector_type(4))) float floatx4;

#define SCALE 0.17677669529663689f
#define MFMA __builtin_amdgcn_mfma_f32_16x16x32_bf16

// ---------------------------------------------------------------------------
// LayerNorm + cyclic shift (-3,-3) + window partition; fp32 in -> bf16 out
// ---------------------------------------------------------------------------
__global__ __launch_bounds__(256)
void ln_window(const float* __restrict__ x, const float* __restrict__ g,
               const float* __restrict__ bta, bf16_t* __restrict__ xw)
{
    const int wv = threadIdx.x >> 6, lane = threadIdx.x & 63;
    const int t = blockIdx.x * 4 + wv;            // token id, < 100352
    const float* row = x + (size_t)t * 192;
    float v0 = row[lane];
    float v1 = row[lane + 64];
    float v2 = row[lane + 128];
    float s  = v0 + v1 + v2;
    float sq = v0 * v0 + v1 * v1 + v2 * v2;
#pragma unroll
    for (int off = 32; off > 0; off >>= 1) {
        s  += __shfl_down(s, off);
        sq += __shfl_down(sq, off);
    }
    s = __shfl(s, 0); sq = __shfl(sq, 0);
    float mu  = s * (1.0f / 192.0f);
    float var = sq * (1.0f / 192.0f) - mu * mu;
    float inv = rsqrtf(var + 1e-5f);

    int b = t / 3136, p = t - b * 3136;
    int hh = p / 56, ww = p - hh * 56;
    int hs = hh - 3; if (hs < 0) hs += 56;
    int ws = ww - 3; if (ws < 0) ws += 56;
    int wh = hs / 7, ii = hs - wh * 7;
    int wwi = ws / 7, jj = ws - wwi * 7;
    size_t orow = ((size_t)(b * 64 + wh * 8 + wwi) * 49 + ii * 7 + jj) * 192;

    xw[orow + lane]       = (bf16_t)((v0 - mu) * inv * g[lane]       + bta[lane]);
    xw[orow + lane + 64]  = (bf16_t)((v1 - mu) * inv * g[lane + 64]  + bta[lane + 64]);
    xw[orow + lane + 128] = (bf16_t)((v2 - mu) * inv * g[lane + 128] + bta[lane + 128]);
}

// ---------------------------------------------------------------------------
// Weight fp32 -> bf16 conversion (qkv_w | proj_w | lin_w concatenated)
// ---------------------------------------------------------------------------
__global__ __launch_bounds__(256)
void convert_weights(const float* __restrict__ a, const float* __restrict__ b,
                     const float* __restrict__ c, bf16_t* __restrict__ out)
{
    int i = blockIdx.x * 256 + threadIdx.x;   // 184320 total
    if (i < 110592)       out[i] = (bf16_t)a[i];
    else if (i < 147456)  out[i] = (bf16_t)b[i - 110592];
    else                  out[i] = (bf16_t)c[i - 147456];
}

// ---------------------------------------------------------------------------
// Pre-combine rel-pos bias + shift mask into C-fragment-ordered table:
// cb2[wh=win*6+h][mt][lane][nt*4+r]  (bf16); j>=49 -> -1e30
// ---------------------------------------------------------------------------
__global__ __launch_bounds__(256)
void build_cb2(const float* __restrict__ table, const int* __restrict__ rpi,
               const float* __restrict__ mask, bf16_t* __restrict__ cb2)
{
    int i = blockIdx.x * 256 + threadIdx.x;   // 1,572,864 total
    int idx = i & 15, lane = (i >> 4) & 63, mt = (i >> 10) & 3, wh = i >> 12;
    int win = wh / 6, h = wh - win * 6;
    int nt = idx >> 2, r = idx & 3;
    int m = mt * 16 + ((lane >> 4)) * 4 + r;
    int j = nt * 16 + (lane & 15);
    float v;
    if (j >= 49)      v = -1e30f;
    else if (m >= 49) v = 0.0f;
    else              v = table[rpi[m * 49 + j] * 6 + h] + mask[win * 2401 + m * 49 + j];
    cb2[i] = (bf16_t)v;
}

// ---------------------------------------------------------------------------
// Fused per-window kernel: qkv GEMM + attention + proj GEMM.
// One block per window (2048), 6 waves, wave h = head h (round-0 structure:
// best measured per-wave efficiency — long wave-private chains, 2 barriers).
//
// LDS SHRUNK 60 KB -> 30 KB so TWO blocks co-reside per CU (the empirical
// limiter across r0/r1/r3 was LDS pool ~64 KB => 1 block at 60 KB).
// Per head ONE [64][40] region (2560 bf16 = 5 KB), serially reused:
//   k -> pull kf -> q -> pull qf -> P(half A) -> pf0 -> P(half B) -> pf1
//   -> vT(tok 0..31) -> vf0 -> PV -> vT(tok 32..63) -> vf1 -> PV
// (all wave-private; per-wave DS ordering makes this barrier-free).
// ctx [64][200] = 12800 elems overlays regions 0..4 (2 block barriers).
// X fragments are re-loaded per-ks (not held) to keep VGPR <= 170 so
// 2 blocks x 6 waves = 3 waves/SIMD fit:  __launch_bounds__(384, 3).
// ---------------------------------------------------------------------------
__global__ __launch_bounds__(384, 3)
void fused_window(const bf16_t* __restrict__ xw, const bf16_t* __restrict__ wcvt,
                  const float* __restrict__ qkv_b, const float* __restrict__ proj_b,
                  const bf16_t* __restrict__ cb2, bf16_t* __restrict__ pob)
{
    __shared__ __align__(16) bf16_t lds[15360];     // 6 * 2560 = 30720 B
    const int tid = threadIdx.x;
    const int h = tid >> 6;                          // head 0..5
    const int lane = tid & 63;
    const int quad = lane >> 4, lr = lane & 15;
    const int w = blockIdx.x;                        // window id 0..2047
    const int wh = (w & 63) * 6 + h;
    bf16_t* R = lds + h * 2560;                      // [64][40] region

    const bf16_t* xb = xw + (size_t)w * 49 * 192;

    // ---- Phase A1: q,k = X @ Wq,Wk (64 tok x 64 cols); x loaded per-ks ----
    floatx4 acc[4][4];
#pragma unroll
    for (int mt = 0; mt < 4; ++mt)
#pragma unroll
        for (int nt = 0; nt < 4; ++nt) acc[mt][nt] = floatx4{0.f,0.f,0.f,0.f};

#pragma unroll
    for (int ks = 0; ks < 6; ++ks) {
        bf16x8 xk[4];
#pragma unroll
        for (int mt = 0; mt < 4; ++mt)
            xk[mt] = *(const bf16x8*)(xb + (size_t)(mt * 16 + lr) * 192 + ks * 32 + quad * 8);
        const bf16_t* wr = wcvt + (size_t)(h * 32 + lr) * 192 + ks * 32 + quad * 8;
        bf16x8 wq0 = *(const bf16x8*)(wr);
        bf16x8 wq1 = *(const bf16x8*)(wr + 16 * 192);
        bf16x8 wk0 = *(const bf16x8*)(wr + 192 * 192);
        bf16x8 wk1 = *(const bf16x8*)(wr + 208 * 192);
#pragma unroll
        for (int mt = 0; mt < 4; ++mt) {
            acc[mt][0] = MFMA(xk[mt], wq0, acc[mt][0], 0, 0, 0);
            acc[mt][1] = MFMA(xk[mt], wq1, acc[mt][1], 0, 0, 0);
            acc[mt][2] = MFMA(xk[mt], wk0, acc[mt][2], 0, 0, 0);
            acc[mt][3] = MFMA(xk[mt], wk1, acc[mt][3], 0, 0, 0);
        }
    }

    // ---- k -> R, pull kf; q -> R (overwrite), pull qf (DS in-order) ----
    bf16x8 qf[4], kf[4];
    {
        float bk0 = qkv_b[192 + h * 32 + lr], bk1 = qkv_b[192 + h * 32 + 16 + lr];
#pragma unroll
        for (int mt = 0; mt < 4; ++mt)
#pragma unroll
            for (int r = 0; r < 4; ++r) {
                int tok = mt * 16 + quad * 4 + r;
                R[tok * 40 + lr]      = (bf16_t)(acc[mt][2][r] + bk0);
                R[tok * 40 + 16 + lr] = (bf16_t)(acc[mt][3][r] + bk1);
            }
#pragma unroll
        for (int t = 0; t < 4; ++t)
            kf[t] = *(const bf16x8*)&R[(t * 16 + lr) * 40 + quad * 8];

        float bq0 = qkv_b[h * 32 + lr], bq1 = qkv_b[h * 32 + 16 + lr];
#pragma unroll
        for (int mt = 0; mt < 4; ++mt)
#pragma unroll
            for (int r = 0; r < 4; ++r) {
                int tok = mt * 16 + quad * 4 + r;
                R[tok * 40 + lr]      = (bf16_t)((acc[mt][0][r] + bq0) * SCALE);
                R[tok * 40 + 16 + lr] = (bf16_t)((acc[mt][1][r] + bq1) * SCALE);
            }
#pragma unroll
        for (int t = 0; t < 4; ++t)
            qf[t] = *(const bf16x8*)&R[(t * 16 + lr) * 40 + quad * 8];
    }

    // ---- QK^T (64x64, K=32) ----
    floatx4 s[4][4];
#pragma unroll
    for (int mt = 0; mt < 4; ++mt)
#pragma unroll
        for (int nt = 0; nt < 4; ++nt) s[mt][nt] = floatx4{0.f,0.f,0.f,0.f};
#pragma unroll
    for (int mt = 0; mt < 4; ++mt)
#pragma unroll
        for (int nt = 0; nt < 4; ++nt)
            s[mt][nt] = MFMA(qf[mt], kf[nt], s[mt][nt], 0, 0, 0);

    // bias + mask (C-frag ordered)
    const bf16_t* cb = cb2 + (((size_t)wh * 4) * 64 + lane) * 16;
#pragma unroll
    for (int mt = 0; mt < 4; ++mt) {
        bf16x8 c0 = *(const bf16x8*)(cb + (size_t)mt * 1024);
        bf16x8 c1 = *(const bf16x8*)(cb + (size_t)mt * 1024 + 8);
#pragma unroll
        for (int r = 0; r < 4; ++r) {
            s[mt][0][r] += (float)c0[r];
            s[mt][1][r] += (float)c0[4 + r];
            s[mt][2][r] += (float)c1[r];
            s[mt][3][r] += (float)c1[4 + r];
        }
    }

    // in-register row softmax (row spread over 16 lr lanes x 4 nt regs)
#pragma unroll
    for (int mt = 0; mt < 4; ++mt) {
#pragma unroll
        for (int r = 0; r < 4; ++r) {
            float mx = fmaxf(fmaxf(s[mt][0][r], s[mt][1][r]),
                             fmaxf(s[mt][2][r], s[mt][3][r]));
#pragma unroll
            for (int off = 1; off < 16; off <<= 1)
                mx = fmaxf(mx, __shfl_xor(mx, off));
            float sum = 0.f;
#pragma unroll
            for (int nt = 0; nt < 4; ++nt) {
                float e = __expf(s[mt][nt][r] - mx);
                s[mt][nt][r] = e; sum += e;
            }
#pragma unroll
            for (int off = 1; off < 16; off <<= 1)
                sum += __shfl_xor(sum, off);
            float inv = 1.0f / sum;
#pragma unroll
            for (int nt = 0; nt < 4; ++nt) s[mt][nt][r] *= inv;
        }
    }

    // ---- P -> R in two 32-key halves (overwrites q); pull pf between ----
#pragma unroll
    for (int mt = 0; mt < 4; ++mt)
#pragma unroll
        for (int nt = 0; nt < 2; ++nt)
#pragma unroll
            for (int r = 0; r < 4; ++r)
                R[(mt * 16 + quad * 4 + r) * 40 + nt * 16 + lr] = (bf16_t)s[mt][nt][r];
    bf16x8 pf0[4];
#pragma unroll
    for (int mt = 0; mt < 4; ++mt)
        pf0[mt] = *(const bf16x8*)&R[(mt * 16 + lr) * 40 + quad * 8];
#pragma unroll
    for (int mt = 0; mt < 4; ++mt)
#pragma unroll
        for (int nt = 2; nt < 4; ++nt)
#pragma unroll
            for (int r = 0; r < 4; ++r)
                R[(mt * 16 + quad * 4 + r) * 40 + (nt - 2) * 16 + lr] = (bf16_t)s[mt][nt][r];
    bf16x8 pf1[4];
#pragma unroll
    for (int mt = 0; mt < 4; ++mt)
        pf1[mt] = *(const bf16x8*)&R[(mt * 16 + lr) * 40 + quad * 8];

    // ---- Phase A2: v = X @ Wv (64 tok x 32 d); x re-loaded per-ks ----
    floatx4 va[4][2];
#pragma unroll
    for (int mt = 0; mt < 4; ++mt) { va[mt][0] = floatx4{0.f,0.f,0.f,0.f}; va[mt][1] = floatx4{0.f,0.f,0.f,0.f}; }
#pragma unroll
    for (int ks = 0; ks < 6; ++ks) {
        bf16x8 xk[4];
#pragma unroll
        for (int mt = 0; mt < 4; ++mt)
            xk[mt] = *(const bf16x8*)(xb + (size_t)(mt * 16 + lr) * 192 + ks * 32 + quad * 8);
        const bf16_t* wr = wcvt + (size_t)(384 + h * 32 + lr) * 192 + ks * 32 + quad * 8;
        bf16x8 wv0 = *(const bf16x8*)(wr);
        bf16x8 wv1 = *(const bf16x8*)(wr + 16 * 192);
#pragma unroll
        for (int mt = 0; mt < 4; ++mt) {
            va[mt][0] = MFMA(xk[mt], wv0, va[mt][0], 0, 0, 0);
            va[mt][1] = MFMA(xk[mt], wv1, va[mt][1], 0, 0, 0);
        }
    }

    // ---- PV in two 32-token K-halves through the single region ----
    floatx4 c[4][2];
#pragma unroll
    for (int mt = 0; mt < 4; ++mt) { c[mt][0] = floatx4{0.f,0.f,0.f,0.f}; c[mt][1] = floatx4{0.f,0.f,0.f,0.f}; }
    {
        float bv0 = qkv_b[384 + h * 32 + lr], bv1 = qkv_b[384 + h * 32 + 16 + lr];
        // half 0: tokens 0..31 (va[0..1]) -> vT rows d=0..31, cols tok 0..31
#pragma unroll
        for (int mt2 = 0; mt2 < 2; ++mt2) {
            bf16x4 p0, p1;
#pragma unroll
            for (int r = 0; r < 4; ++r) {
                p0[r] = (bf16_t)(va[mt2][0][r] + bv0);
                p1[r] = (bf16_t)(va[mt2][1][r] + bv1);
            }
            *(bf16x4*)&R[lr * 40 + mt2 * 16 + quad * 4]        = p0;
            *(bf16x4*)&R[(16 + lr) * 40 + mt2 * 16 + quad * 4] = p1;
        }
        bf16x8 vf0[2];
#pragma unroll
        for (int nt = 0; nt < 2; ++nt)
            vf0[nt] = *(const bf16x8*)&R[(nt * 16 + lr) * 40 + quad * 8];
#pragma unroll
        for (int mt = 0; mt < 4; ++mt)
#pragma unroll
            for (int nt = 0; nt < 2; ++nt)
                c[mt][nt] = MFMA(pf0[mt], vf0[nt], c[mt][nt], 0, 0, 0);
        // half 1: tokens 32..63 (va[2..3])
#pragma unroll
        for (int mt2 = 0; mt2 < 2; ++mt2) {
            bf16x4 p0, p1;
#pragma unroll
            for (int r = 0; r < 4; ++r) {
                p0[r] = (bf16_t)(va[mt2 + 2][0][r] + bv0);
                p1[r] = (bf16_t)(va[mt2 + 2][1][r] + bv1);
            }
            *(bf16x4*)&R[lr * 40 + mt2 * 16 + quad * 4]        = p0;
            *(bf16x4*)&R[(16 + lr) * 40 + mt2 * 16 + quad * 4] = p1;
        }
        bf16x8 vf1[2];
#pragma unroll
        for (int nt = 0; nt < 2; ++nt)
            vf1[nt] = *(const bf16x8*)&R[(nt * 16 + lr) * 40 + quad * 8];
#pragma unroll
        for (int mt = 0; mt < 4; ++mt)
#pragma unroll
            for (int nt = 0; nt < 2; ++nt)
                c[mt][nt] = MFMA(pf1[mt], vf1[nt], c[mt][nt], 0, 0, 0);
    }

    // ---- ctx -> shared [64][200] (overlays head regions 0..4) ----
    __syncthreads();
#pragma unroll
    for (int mt = 0; mt < 4; ++mt)
#pragma unroll
        for (int nt = 0; nt < 2; ++nt)
#pragma unroll
            for (int r = 0; r < 4; ++r)
                lds[(mt * 16 + quad * 4 + r) * 200 + h * 32 + nt * 16 + lr] = (bf16_t)c[mt][nt][r];
    __syncthreads();

    // ---- proj: ctx[64x192] @ proj_w -> cols [h*32, h*32+32) ----
    const bf16_t* pw = wcvt + 110592;
    floatx4 pr[4][2];
#pragma unroll
    for (int mt = 0; mt < 4; ++mt) { pr[mt][0] = floatx4{0.f,0.f,0.f,0.f}; pr[mt][1] = floatx4{0.f,0.f,0.f,0.f}; }
#pragma unroll
    for (int ks = 0; ks < 6; ++ks) {
        bf16x8 w0 = *(const bf16x8*)(pw + (size_t)(h * 32 + lr) * 192 + ks * 32 + quad * 8);
        bf16x8 w1 = *(const bf16x8*)(pw + (size_t)(h * 32 + 16 + lr) * 192 + ks * 32 + quad * 8);
#pragma unroll
        for (int mt = 0; mt < 4; ++mt) {
            bf16x8 af = *(const bf16x8*)&lds[(mt * 16 + lr) * 200 + ks * 32 + quad * 8];
            pr[mt][0] = MFMA(af, w0, pr[mt][0], 0, 0, 0);
            pr[mt][1] = MFMA(af, w1, pr[mt][1], 0, 0, 0);
        }
    }
    // epilogue: bias + window-reverse + unshift scatter (only global write)
    {
        float pb0 = proj_b[h * 32 + lr], pb1 = proj_b[h * 32 + 16 + lr];
        int b = w >> 6, widx = w & 63;
        int whh = widx >> 3, www = widx & 7;
#pragma unroll
        for (int mt = 0; mt < 4; ++mt)
#pragma unroll
            for (int r = 0; r < 4; ++r) {
                int m = mt * 16 + quad * 4 + r;
                if (m < 49) {
                    int ii = m / 7, jj = m - ii * 7;
                    int hs = whh * 7 + ii + 3; if (hs >= 56) hs -= 56;
                    int ws2 = www * 7 + jj + 3; if (ws2 >= 56) ws2 -= 56;
                    size_t base = ((size_t)(b * 3136 + hs * 56 + ws2)) * 192 + h * 32;
                    pob[base + lr]      = (bf16_t)(pr[mt][0][r] + pb0);
                    pob[base + 16 + lr] = (bf16_t)(pr[mt][1][r] + pb1);
                }
            }
    }
}

// ---------------------------------------------------------------------------
// lin GEMM (LDS-free): out = resid + gelu(A @ lin_w^T + b), fp32 out.
// Block: 4 waves, tile 128m x 64n; wave tile 32m x 64n. grid (3, 784).
// ---------------------------------------------------------------------------
__global__ __launch_bounds__(256)
void lin_gemm(const bf16_t* __restrict__ A, const bf16_t* __restrict__ W,
              const float* __restrict__ bias, const float* __restrict__ resid,
              float* __restrict__ out)
{
    const int tid = threadIdx.x;
    const int wave = tid >> 6, lane = tid & 63;
    const int quad = lane >> 4, lr = lane & 15;
    const int n0 = blockIdx.x * 64;
    const int m0 = blockIdx.y * 128 + wave * 32;

    const bf16_t* a0p = A + (size_t)(m0 + lr) * 192 + quad * 8;
    const bf16_t* a1p = A + (size_t)(m0 + 16 + lr) * 192 + quad * 8;
    const bf16_t* w0p = W + (size_t)(n0 + lr) * 192 + quad * 8;
    const bf16_t* w1p = w0p + 16 * 192;
    const bf16_t* w2p = w0p + 32 * 192;
    const bf16_t* w3p = w0p + 48 * 192;

    floatx4 acc[2][4];
#pragma unroll
    for (int mt = 0; mt < 2; ++mt)
#pragma unroll
        for (int nt = 0; nt < 4; ++nt) acc[mt][nt] = floatx4{0.f,0.f,0.f,0.f};

#pragma unroll
    for (int ks = 0; ks < 6; ++ks) {
        bf16x8 af0 = *(const bf16x8*)(a0p + ks * 32);
        bf16x8 af1 = *(const bf16x8*)(a1p + ks * 32);
        bf16x8 wf0 = *(const bf16x8*)(w0p + ks * 32);
        bf16x8 wf1 = *(const bf16x8*)(w1p + ks * 32);
        bf16x8 wf2 = *(const bf16x8*)(w2p + ks * 32);
        bf16x8 wf3 = *(const bf16x8*)(w3p + ks * 32);
        acc[0][0] = MFMA(af0, wf0, acc[0][0], 0, 0, 0);
        acc[1][0] = MFMA(af1, wf0, acc[1][0], 0, 0, 0);
        acc[0][1] = MFMA(af0, wf1, acc[0][1], 0, 0, 0);
        acc[1][1] = MFMA(af1, wf1, acc[1][1], 0, 0, 0);
        acc[0][2] = MFMA(af0, wf2, acc[0][2], 0, 0, 0);
        acc[1][2] = MFMA(af1, wf2, acc[1][2], 0, 0, 0);
        acc[0][3] = MFMA(af0, wf3, acc[0][3], 0, 0, 0);
        acc[1][3] = MFMA(af1, wf3, acc[1][3], 0, 0, 0);
    }

#pragma unroll
    for (int mt = 0; mt < 2; ++mt)
#pragma unroll
    for (int nt = 0; nt < 4; ++nt) {
        int n = n0 + nt * 16 + lr;
        float bv = bias[n];
#pragma unroll
        for (int r = 0; r < 4; ++r) {
            int m = m0 + mt * 16 + quad * 4 + r;
            float val = acc[mt][nt][r] + bv;
            float gx = 0.5f * val * (1.0f + erff(val * 0.70710678118654752f));
            out[(size_t)m * 192 + n] = resid[(size_t)m * 192 + n] + gx;
        }
    }
}

// ---------------------------------------------------------------------------
extern "C" void kernel_launch(void* const* d_in, const int* in_sizes, int n_in,
                              void* d_out, int out_size, void* d_ws, size_t ws_size,
                              hipStream_t stream)
{
    const float* inp    = (const float*)d_in[0];
    const float* mask   = (const float*)d_in[1];
    const float* g      = (const float*)d_in[2];
    const float* bta    = (const float*)d_in[3];
    const float* qkv_w  = (const float*)d_in[4];
    const float* qkv_b  = (const float*)d_in[5];
    const float* table  = (const float*)d_in[6];
    const int*   rpi    = (const int*)d_in[7];
    const float* proj_w = (const float*)d_in[8];
    const float* proj_b = (const float*)d_in[9];
    const float* lin_w  = (const float*)d_in[10];
    const float* lin_b  = (const float*)d_in[11];
    float* out = (float*)d_out;

    char* ws = (char*)d_ws;
    bf16_t* xw   = (bf16_t*)(ws);                 // 38,535,168 B (+64-row slack)
    bf16_t* pob  = (bf16_t*)(ws + 40000000);      // 38,535,168 B
    bf16_t* wcvt = (bf16_t*)(ws + 80000000);      //    368,640 B
    bf16_t* cb2  = (bf16_t*)(ws + 80400000);      //  3,145,728 B  (end ~83.5 MB)

    convert_weights<<<720, 256, 0, stream>>>(qkv_w, proj_w, lin_w, wcvt);
    build_cb2<<<6144, 256, 0, stream>>>(table, rpi, mask, cb2);
    ln_window<<<25088, 256, 0, stream>>>(inp, g, bta, xw);
    fused_window<<<2048, 384, 0, stream>>>(xw, wcvt, qkv_b, proj_b, cb2, pob);
    lin_gemm<<<dim3(3, 784), 256, 0, stream>>>(pob, wcvt + 147456, lin_b, inp, out);
}

// Round 5
// 385.738 us; speedup vs baseline: 1.1595x; 1.1595x over previous
//
#include <hip/hip_runtime.h>
#include <hip/hip_bf16.h>
#include <math.h>

typedef __bf16 bf16_t;
typedef __attribute__((ext_vector_type(8))) __bf16 bf16x8;
typedef __attribute__((ext_vector_type(4))) float floatx4;

#define SCALE 0.17677669529663689f
#define MFMA __builtin_amdgcn_mfma_f32_16x16x32_bf16

// ---------------------------------------------------------------------------
// LayerNorm + cyclic shift (-3,-3) + window partition; fp32 in -> bf16 out
// ---------------------------------------------------------------------------
__global__ __launch_bounds__(256)
void ln_window(const float* __restrict__ x, const float* __restrict__ g,
               const float* __restrict__ bta, bf16_t* __restrict__ xw)
{
    const int wv = threadIdx.x >> 6, lane = threadIdx.x & 63;
    const int t = blockIdx.x * 4 + wv;            // token id, < 100352
    const float* row = x + (size_t)t * 192;
    float v0 = row[lane];
    float v1 = row[lane + 64];
    float v2 = row[lane + 128];
    float s  = v0 + v1 + v2;
    float sq = v0 * v0 + v1 * v1 + v2 * v2;
#pragma unroll
    for (int off = 32; off > 0; off >>= 1) {
        s  += __shfl_down(s, off);
        sq += __shfl_down(sq, off);
    }
    s = __shfl(s, 0); sq = __shfl(sq, 0);
    float mu  = s * (1.0f / 192.0f);
    float var = sq * (1.0f / 192.0f) - mu * mu;
    float inv = rsqrtf(var + 1e-5f);

    int b = t / 3136, p = t - b * 3136;
    int hh = p / 56, ww = p - hh * 56;
    int hs = hh - 3; if (hs < 0) hs += 56;
    int ws = ww - 3; if (ws < 0) ws += 56;
    int wh = hs / 7, ii = hs - wh * 7;
    int wwi = ws / 7, jj = ws - wwi * 7;
    size_t orow = ((size_t)(b * 64 + wh * 8 + wwi) * 49 + ii * 7 + jj) * 192;

    xw[orow + lane]       = (bf16_t)((v0 - mu) * inv * g[lane]       + bta[lane]);
    xw[orow + lane + 64]  = (bf16_t)((v1 - mu) * inv * g[lane + 64]  + bta[lane + 64]);
    xw[orow + lane + 128] = (bf16_t)((v2 - mu) * inv * g[lane + 128] + bta[lane + 128]);
}

// ---------------------------------------------------------------------------
// qkv_w fp32 -> bf16 conversion (110592 elems)
// ---------------------------------------------------------------------------
__global__ __launch_bounds__(256)
void convert_weights(const float* __restrict__ a, bf16_t* __restrict__ out)
{
    int i = blockIdx.x * 256 + threadIdx.x;
    out[i] = (bf16_t)a[i];
}

// ---------------------------------------------------------------------------
// Fold proj into lin:  Wf = lin_w @ proj_w  (192x192, fp32 accum -> bf16),
// bf = lin_b + lin_w @ proj_b.   (proj and lin have no nonlinearity between
// them; the window-reverse permutation commutes with per-token channel GEMMs)
// ---------------------------------------------------------------------------
__global__ __launch_bounds__(192)
void fold_weights(const float* __restrict__ lw, const float* __restrict__ pw,
                  const float* __restrict__ pb, const float* __restrict__ lb,
                  bf16_t* __restrict__ wf, float* __restrict__ bfb)
{
    int o = blockIdx.x, i = threadIdx.x;          // 192 x 192
    float acc = 0.f;
    for (int c = 0; c < 192; ++c)
        acc += lw[o * 192 + c] * pw[c * 192 + i];
    wf[o * 192 + i] = (bf16_t)acc;
    if (i == 0) {
        float b = lb[o];
        for (int c = 0; c < 192; ++c) b += lw[o * 192 + c] * pb[c];
        bfb[o] = b;
    }
}

// ---------------------------------------------------------------------------
// Pre-combine rel-pos bias + shift mask into C-fragment-ordered table:
// cb2[wh=win*6+h][mt][lane][nt*4+r]  (bf16); j>=49 -> -1e30
// ---------------------------------------------------------------------------
__global__ __launch_bounds__(256)
void build_cb2(const float* __restrict__ table, const int* __restrict__ rpi,
               const float* __restrict__ mask, bf16_t* __restrict__ cb2)
{
    int i = blockIdx.x * 256 + threadIdx.x;   // 1,572,864 total
    int idx = i & 15, lane = (i >> 4) & 63, mt = (i >> 10) & 3, wh = i >> 12;
    int win = wh / 6, h = wh - win * 6;
    int nt = idx >> 2, r = idx & 3;
    int m = mt * 16 + ((lane >> 4)) * 4 + r;
    int j = nt * 16 + (lane & 15);
    float v;
    if (j >= 49)      v = -1e30f;
    else if (m >= 49) v = 0.0f;
    else              v = table[rpi[m * 49 + j] * 6 + h] + mask[win * 2401 + m * 49 + j];
    cb2[i] = (bf16_t)v;
}

// ---------------------------------------------------------------------------
// Fused per-window kernel: qkv GEMM + attention (proj FOLDED into lin_gemm).
// One block per window (2048), 6 waves, wave h = head h.  Round-0 structure
// (best measured per-wave efficiency), now 100% wave-private: ZERO barriers.
// LDS: 6 regions of 5120 bf16 (10.24 KB) = 60 KB total.
//   region/head: [q 64x40 | k 64x40] -> overlaid by P 64x72 -> rows 0..31
//   overlaid by vT 32x72 (P fragments pulled to regs first; DS is in-order
//   per wave so no barrier needed for wave-private reuse).
// Global write: ctx (incl. v-bias; softmax rows sum to 1 so P@bv = bv)
// scattered to window-reversed spatial layout.
// ---------------------------------------------------------------------------
__global__ __launch_bounds__(384)
void fused_window(const bf16_t* __restrict__ xw, const bf16_t* __restrict__ wcvt,
                  const float* __restrict__ qkv_b,
                  const bf16_t* __restrict__ cb2, bf16_t* __restrict__ pob)
{
    __shared__ __align__(16) bf16_t lds[30720];     // 6 * 5120
    const int tid = threadIdx.x;
    const int h = tid >> 6;                          // head 0..5
    const int lane = tid & 63;
    const int quad = lane >> 4, lr = lane & 15;
    const int w = blockIdx.x;                        // window id 0..2047
    const int wh = (w & 63) * 6 + h;
    bf16_t* R = lds + h * 5120;

    // ---- X A-fragments, held in registers (window rows are contiguous) ----
    const bf16_t* xb = xw + (size_t)w * 49 * 192;
    bf16x8 xf[4][6];
#pragma unroll
    for (int mt = 0; mt < 4; ++mt)
#pragma unroll
        for (int ks = 0; ks < 6; ++ks)
            xf[mt][ks] = *(const bf16x8*)(xb + (size_t)(mt * 16 + lr) * 192 + ks * 32 + quad * 8);

    // ---- Phase A1: q,k = X @ Wq,Wk  (64 tok x 64 cols) ----
    floatx4 acc[4][4];
#pragma unroll
    for (int mt = 0; mt < 4; ++mt)
#pragma unroll
        for (int nt = 0; nt < 4; ++nt) acc[mt][nt] = floatx4{0.f,0.f,0.f,0.f};

#pragma unroll
    for (int ks = 0; ks < 6; ++ks) {
        bf16x8 wf0 = *(const bf16x8*)(wcvt + (size_t)(h * 32 + lr) * 192 + ks * 32 + quad * 8);
        bf16x8 wf1 = *(const bf16x8*)(wcvt + (size_t)(h * 32 + 16 + lr) * 192 + ks * 32 + quad * 8);
        bf16x8 wf2 = *(const bf16x8*)(wcvt + (size_t)(192 + h * 32 + lr) * 192 + ks * 32 + quad * 8);
        bf16x8 wf3 = *(const bf16x8*)(wcvt + (size_t)(192 + h * 32 + 16 + lr) * 192 + ks * 32 + quad * 8);
#pragma unroll
        for (int mt = 0; mt < 4; ++mt) {
            acc[mt][0] = MFMA(xf[mt][ks], wf0, acc[mt][0], 0, 0, 0);
            acc[mt][1] = MFMA(xf[mt][ks], wf1, acc[mt][1], 0, 0, 0);
            acc[mt][2] = MFMA(xf[mt][ks], wf2, acc[mt][2], 0, 0, 0);
            acc[mt][3] = MFMA(xf[mt][ks], wf3, acc[mt][3], 0, 0, 0);
        }
    }
    {
        float bq0 = qkv_b[h * 32 + lr],       bq1 = qkv_b[h * 32 + 16 + lr];
        float bk0 = qkv_b[192 + h * 32 + lr], bk1 = qkv_b[192 + h * 32 + 16 + lr];
#pragma unroll
        for (int mt = 0; mt < 4; ++mt)
#pragma unroll
            for (int r = 0; r < 4; ++r) {
                int tok = mt * 16 + quad * 4 + r;
                R[tok * 40 + lr]             = (bf16_t)((acc[mt][0][r] + bq0) * SCALE);
                R[tok * 40 + 16 + lr]        = (bf16_t)((acc[mt][1][r] + bq1) * SCALE);
                R[2560 + tok * 40 + lr]      = (bf16_t)(acc[mt][2][r] + bk0);
                R[2560 + tok * 40 + 16 + lr] = (bf16_t)(acc[mt][3][r] + bk1);
            }
    }

    // ---- QK^T (64x64, K=32) ----
    bf16x8 qf[4], kf[4];
#pragma unroll
    for (int t = 0; t < 4; ++t) {
        qf[t] = *(const bf16x8*)&R[(t * 16 + lr) * 40 + quad * 8];
        kf[t] = *(const bf16x8*)&R[2560 + (t * 16 + lr) * 40 + quad * 8];
    }
    floatx4 s[4][4];
#pragma unroll
    for (int mt = 0; mt < 4; ++mt)
#pragma unroll
        for (int nt = 0; nt < 4; ++nt) s[mt][nt] = floatx4{0.f,0.f,0.f,0.f};
#pragma unroll
    for (int mt = 0; mt < 4; ++mt)
#pragma unroll
        for (int nt = 0; nt < 4; ++nt)
            s[mt][nt] = MFMA(qf[mt], kf[nt], s[mt][nt], 0, 0, 0);

    // bias + mask (C-frag ordered)
    const bf16_t* cb = cb2 + (((size_t)wh * 4) * 64 + lane) * 16;
#pragma unroll
    for (int mt = 0; mt < 4; ++mt) {
        bf16x8 c0 = *(const bf16x8*)(cb + (size_t)mt * 1024);
        bf16x8 c1 = *(const bf16x8*)(cb + (size_t)mt * 1024 + 8);
#pragma unroll
        for (int r = 0; r < 4; ++r) {
            s[mt][0][r] += (float)c0[r];
            s[mt][1][r] += (float)c0[4 + r];
            s[mt][2][r] += (float)c1[r];
            s[mt][3][r] += (float)c1[4 + r];
        }
    }

    // in-register row softmax (row spread over 16 lr lanes x 4 nt regs)
#pragma unroll
    for (int mt = 0; mt < 4; ++mt) {
#pragma unroll
        for (int r = 0; r < 4; ++r) {
            float mx = fmaxf(fmaxf(s[mt][0][r], s[mt][1][r]),
                             fmaxf(s[mt][2][r], s[mt][3][r]));
#pragma unroll
            for (int off = 1; off < 16; off <<= 1)
                mx = fmaxf(mx, __shfl_xor(mx, off));
            float sum = 0.f;
#pragma unroll
            for (int nt = 0; nt < 4; ++nt) {
                float e = __expf(s[mt][nt][r] - mx);
                s[mt][nt][r] = e; sum += e;
            }
#pragma unroll
            for (int off = 1; off < 16; off <<= 1)
                sum += __shfl_xor(sum, off);
            float inv = 1.0f / sum;
#pragma unroll
            for (int nt = 0; nt < 4; ++nt) s[mt][nt][r] *= inv;
        }
    }

    // ---- P -> LDS (overwrites q/k; wave-private), pull A-frags of P ----
#pragma unroll
    for (int mt = 0; mt < 4; ++mt)
#pragma unroll
        for (int nt = 0; nt < 4; ++nt)
#pragma unroll
            for (int r = 0; r < 4; ++r)
                R[(mt * 16 + quad * 4 + r) * 72 + nt * 16 + lr] = (bf16_t)s[mt][nt][r];
    bf16x8 pf[4][2];
#pragma unroll
    for (int mt = 0; mt < 4; ++mt)
#pragma unroll
        for (int kt = 0; kt < 2; ++kt)
            pf[mt][kt] = *(const bf16x8*)&R[(mt * 16 + lr) * 72 + kt * 32 + quad * 8];

    // ---- Phase A2: v = X @ Wv (64 tok x 32 d) ----
    floatx4 va[4][2];
#pragma unroll
    for (int mt = 0; mt < 4; ++mt) { va[mt][0] = floatx4{0.f,0.f,0.f,0.f}; va[mt][1] = floatx4{0.f,0.f,0.f,0.f}; }
#pragma unroll
    for (int ks = 0; ks < 6; ++ks) {
        bf16x8 wv0 = *(const bf16x8*)(wcvt + (size_t)(384 + h * 32 + lr) * 192 + ks * 32 + quad * 8);
        bf16x8 wv1 = *(const bf16x8*)(wcvt + (size_t)(384 + h * 32 + 16 + lr) * 192 + ks * 32 + quad * 8);
#pragma unroll
        for (int mt = 0; mt < 4; ++mt) {
            va[mt][0] = MFMA(xf[mt][ks], wv0, va[mt][0], 0, 0, 0);
            va[mt][1] = MFMA(xf[mt][ks], wv1, va[mt][1], 0, 0, 0);
        }
    }
    // vT into P region rows 0..31 (P frags already in regs; DS in-order)
    {
        float bv0 = qkv_b[384 + h * 32 + lr], bv1 = qkv_b[384 + h * 32 + 16 + lr];
#pragma unroll
        for (int mt = 0; mt < 4; ++mt)
#pragma unroll
            for (int r = 0; r < 4; ++r) {
                int tok = mt * 16 + quad * 4 + r;
                R[lr * 72 + tok]        = (bf16_t)(va[mt][0][r] + bv0);
                R[(16 + lr) * 72 + tok] = (bf16_t)(va[mt][1][r] + bv1);
            }
    }

    // ---- PV (64 x 32, K=64) ----
    bf16x8 vf[2][2];
#pragma unroll
    for (int nt = 0; nt < 2; ++nt)
#pragma unroll
        for (int kt = 0; kt < 2; ++kt)
            vf[nt][kt] = *(const bf16x8*)&R[(nt * 16 + lr) * 72 + kt * 32 + quad * 8];
    floatx4 c[4][2];
#pragma unroll
    for (int mt = 0; mt < 4; ++mt) { c[mt][0] = floatx4{0.f,0.f,0.f,0.f}; c[mt][1] = floatx4{0.f,0.f,0.f,0.f}; }
#pragma unroll
    for (int mt = 0; mt < 4; ++mt)
#pragma unroll
        for (int nt = 0; nt < 2; ++nt) {
            c[mt][nt] = MFMA(pf[mt][0], vf[nt][0], c[mt][nt], 0, 0, 0);
            c[mt][nt] = MFMA(pf[mt][1], vf[nt][1], c[mt][nt], 0, 0, 0);
        }

    // ---- epilogue: ctx scatter (window-reverse + unshift); proj folded away ----
    {
        int b = w >> 6, widx = w & 63;
        int whh = widx >> 3, www = widx & 7;
#pragma unroll
        for (int mt = 0; mt < 4; ++mt)
#pragma unroll
            for (int r = 0; r < 4; ++r) {
                int m = mt * 16 + quad * 4 + r;
                if (m < 49) {
                    int ii = m / 7, jj = m - ii * 7;
                    int hs = whh * 7 + ii + 3; if (hs >= 56) hs -= 56;
                    int ws2 = www * 7 + jj + 3; if (ws2 >= 56) ws2 -= 56;
                    size_t base = ((size_t)(b * 3136 + hs * 56 + ws2)) * 192 + h * 32;
                    pob[base + lr]      = (bf16_t)c[mt][0][r];
                    pob[base + 16 + lr] = (bf16_t)c[mt][1][r];
                }
            }
    }
}

// ---------------------------------------------------------------------------
// lin GEMM (LDS-free): out = resid + gelu(A @ Wf^T + bf), fp32 out.
// Wf = lin_w @ proj_w (folded), bf = lin_b + lin_w @ proj_b.
// Block: 4 waves, tile 128m x 64n; wave tile 32m x 64n. grid (3, 784).
// ---------------------------------------------------------------------------
__global__ __launch_bounds__(256)
void lin_gemm(const bf16_t* __restrict__ A, const bf16_t* __restrict__ W,
              const float* __restrict__ bias, const float* __restrict__ resid,
              float* __restrict__ out)
{
    const int tid = threadIdx.x;
    const int wave = tid >> 6, lane = tid & 63;
    const int quad = lane >> 4, lr = lane & 15;
    const int n0 = blockIdx.x * 64;
    const int m0 = blockIdx.y * 128 + wave * 32;

    const bf16_t* a0p = A + (size_t)(m0 + lr) * 192 + quad * 8;
    const bf16_t* a1p = A + (size_t)(m0 + 16 + lr) * 192 + quad * 8;
    const bf16_t* w0p = W + (size_t)(n0 + lr) * 192 + quad * 8;
    const bf16_t* w1p = w0p + 16 * 192;
    const bf16_t* w2p = w0p + 32 * 192;
    const bf16_t* w3p = w0p + 48 * 192;

    floatx4 acc[2][4];
#pragma unroll
    for (int mt = 0; mt < 2; ++mt)
#pragma unroll
        for (int nt = 0; nt < 4; ++nt) acc[mt][nt] = floatx4{0.f,0.f,0.f,0.f};

#pragma unroll
    for (int ks = 0; ks < 6; ++ks) {
        bf16x8 af0 = *(const bf16x8*)(a0p + ks * 32);
        bf16x8 af1 = *(const bf16x8*)(a1p + ks * 32);
        bf16x8 wf0 = *(const bf16x8*)(w0p + ks * 32);
        bf16x8 wf1 = *(const bf16x8*)(w1p + ks * 32);
        bf16x8 wf2 = *(const bf16x8*)(w2p + ks * 32);
        bf16x8 wf3 = *(const bf16x8*)(w3p + ks * 32);
        acc[0][0] = MFMA(af0, wf0, acc[0][0], 0, 0, 0);
        acc[1][0] = MFMA(af1, wf0, acc[1][0], 0, 0, 0);
        acc[0][1] = MFMA(af0, wf1, acc[0][1], 0, 0, 0);
        acc[1][1] = MFMA(af1, wf1, acc[1][1], 0, 0, 0);
        acc[0][2] = MFMA(af0, wf2, acc[0][2], 0, 0, 0);
        acc[1][2] = MFMA(af1, wf2, acc[1][2], 0, 0, 0);
        acc[0][3] = MFMA(af0, wf3, acc[0][3], 0, 0, 0);
        acc[1][3] = MFMA(af1, wf3, acc[1][3], 0, 0, 0);
    }

#pragma unroll
    for (int mt = 0; mt < 2; ++mt)
#pragma unroll
    for (int nt = 0; nt < 4; ++nt) {
        int n = n0 + nt * 16 + lr;
        float bv = bias[n];
#pragma unroll
        for (int r = 0; r < 4; ++r) {
            int m = m0 + mt * 16 + quad * 4 + r;
            float val = acc[mt][nt][r] + bv;
            float gx = 0.5f * val * (1.0f + erff(val * 0.70710678118654752f));
            out[(size_t)m * 192 + n] = resid[(size_t)m * 192 + n] + gx;
        }
    }
}

// ---------------------------------------------------------------------------
extern "C" void kernel_launch(void* const* d_in, const int* in_sizes, int n_in,
                              void* d_out, int out_size, void* d_ws, size_t ws_size,
                              hipStream_t stream)
{
    const float* inp    = (const float*)d_in[0];
    const float* mask   = (const float*)d_in[1];
    const float* g      = (const float*)d_in[2];
    const float* bta    = (const float*)d_in[3];
    const float* qkv_w  = (const float*)d_in[4];
    const float* qkv_b  = (const float*)d_in[5];
    const float* table  = (const float*)d_in[6];
    const int*   rpi    = (const int*)d_in[7];
    const float* proj_w = (const float*)d_in[8];
    const float* proj_b = (const float*)d_in[9];
    const float* lin_w  = (const float*)d_in[10];
    const float* lin_b  = (const float*)d_in[11];
    float* out = (float*)d_out;

    char* ws = (char*)d_ws;
    bf16_t* xw   = (bf16_t*)(ws);                 // 38,535,168 B (+64-row slack)
    bf16_t* pob  = (bf16_t*)(ws + 40000000);      // 38,535,168 B  (ctx, bf16)
    bf16_t* wcvt = (bf16_t*)(ws + 80000000);      // qkv 221,184 B | Wf 73,728 B
    float*  bfb  = (float*)(ws + 80000000 + 294912);  // 768 B folded bias
    bf16_t* cb2  = (bf16_t*)(ws + 80400000);      //  3,145,728 B  (end ~83.5 MB)
    bf16_t* wf   = wcvt + 110592;

    convert_weights<<<432, 256, 0, stream>>>(qkv_w, wcvt);
    fold_weights<<<192, 192, 0, stream>>>(lin_w, proj_w, proj_b, lin_b, wf, bfb);
    build_cb2<<<6144, 256, 0, stream>>>(table, rpi, mask, cb2);
    ln_window<<<25088, 256, 0, stream>>>(inp, g, bta, xw);
    fused_window<<<2048, 384, 0, stream>>>(xw, wcvt, qkv_b, cb2, pob);
    lin_gemm<<<dim3(3, 784), 256, 0, stream>>>(pob, wf, bfb, inp, out);
}

// Round 6
// 379.835 us; speedup vs baseline: 1.1775x; 1.0155x over previous
//
#include <hip/hip_runtime.h>
#include <hip/hip_bf16.h>
#include <math.h>

typedef __bf16 bf16_t;
typedef __attribute__((ext_vector_type(8))) __bf16 bf16x8;
typedef __attribute__((ext_vector_type(4))) float floatx4;

#define SCALE 0.17677669529663689f
#define MFMA __builtin_amdgcn_mfma_f32_16x16x32_bf16

// ---------------------------------------------------------------------------
// prep: one launch for all constant-data preprocessing.
//  blocks [0,6144)     : cb2 = rel-pos bias + shift mask, C-frag ordered
//  blocks [6144,6576)  : qkv_w fp32 -> bf16
//  blocks [6576,6768)  : fold proj into lin: Wf = lin_w @ proj_w (bf16),
//                        bf = lin_b + lin_w @ proj_b
// ---------------------------------------------------------------------------
__global__ __launch_bounds__(256)
void prep(const float* __restrict__ table, const int* __restrict__ rpi,
          const float* __restrict__ mask, const float* __restrict__ qkv_w,
          const float* __restrict__ lw, const float* __restrict__ pw,
          const float* __restrict__ pb, const float* __restrict__ lb,
          bf16_t* __restrict__ cb2, bf16_t* __restrict__ wcvt,
          bf16_t* __restrict__ wfo, float* __restrict__ bfb)
{
    const int blk = blockIdx.x, tid = threadIdx.x;
    if (blk < 6144) {
        int i = blk * 256 + tid;   // 1,572,864 total
        int idx = i & 15, lane = (i >> 4) & 63, mt = (i >> 10) & 3, wh = i >> 12;
        int win = wh / 6, h = wh - win * 6;
        int nt = idx >> 2, r = idx & 3;
        int m = mt * 16 + ((lane >> 4)) * 4 + r;
        int j = nt * 16 + (lane & 15);
        float v;
        if (j >= 49)      v = -1e30f;
        else if (m >= 49) v = 0.0f;
        else              v = table[rpi[m * 49 + j] * 6 + h] + mask[win * 2401 + m * 49 + j];
        cb2[i] = (bf16_t)v;
    } else if (blk < 6576) {
        int i = (blk - 6144) * 256 + tid;   // 110592 total, exact
        wcvt[i] = (bf16_t)qkv_w[i];
    } else {
        int o = blk - 6576, i = tid;        // 192 x 192
        if (i < 192) {
            float acc = 0.f;
            for (int c = 0; c < 192; ++c)
                acc += lw[o * 192 + c] * pw[c * 192 + i];
            wfo[o * 192 + i] = (bf16_t)acc;
            if (i == 0) {
                float b = lb[o];
                for (int c = 0; c < 192; ++c) b += lw[o * 192 + c] * pb[c];
                bfb[o] = b;
            }
        }
    }
}

// ---------------------------------------------------------------------------
// MEGAKERNEL: LN + shift + window partition + qkv GEMM + attention +
// folded (proj.lin) GEMM + gelu + residual, all per-window in one block.
// One block per window (2048), 6 waves, wave h = head h.
//
// LDS: XL [64][200] bf16 (25.6 KB) = X tile, later overlaid by ctx;
//      lds 6 x 5120 bf16 (60 KB)   = per-head [q 64x40 | k 64x40] regions,
//      overlaid by P 64x72 / vT 32x72 (wave-private, DS in-order).
// Barriers: (1) X staged, (2) xf pulled -> XL free for ctx, (3) ctx staged.
// Eliminates xw & pob global round-trips and 2 kernel launches (r5 lesson:
// non-fused kernels+overhead cost ~225 us vs ~60 us of roofline work).
// ---------------------------------------------------------------------------
__global__ __launch_bounds__(384)
void fused_window(const float* __restrict__ inp, const float* __restrict__ g,
                  const float* __restrict__ bta, const bf16_t* __restrict__ wcvt,
                  const float* __restrict__ qkv_b, const bf16_t* __restrict__ cb2,
                  const bf16_t* __restrict__ wfo, const float* __restrict__ bfb,
                  float* __restrict__ out)
{
    __shared__ __align__(16) bf16_t XL[64 * 200];    // 25600 B (X tile -> ctx)
    __shared__ __align__(16) bf16_t lds[30720];      // 6 * 5120 = 60 KB
    const int tid = threadIdx.x;
    const int h = tid >> 6;                          // head / wave 0..5
    const int lane = tid & 63;
    const int quad = lane >> 4, lr = lane & 15;
    const int w = blockIdx.x;                        // window id 0..2047
    const int wh = (w & 63) * 6 + h;
    bf16_t* R = lds + h * 5120;

    const int b = w >> 6, widx = w & 63;
    const int whh = widx >> 3, www = widx & 7;

    // ---- Phase 0: LayerNorm + gather (shift/partition) into XL ----
    {
        float g0 = g[lane], g1 = g[lane + 64], g2 = g[lane + 128];
        float b0 = bta[lane], b1 = bta[lane + 64], b2 = bta[lane + 128];
        for (int t = h; t < 49; t += 6) {
            int ii = t / 7, jj = t - ii * 7;
            int hh2 = whh * 7 + ii + 3; if (hh2 >= 56) hh2 -= 56;
            int ww2 = www * 7 + jj + 3; if (ww2 >= 56) ww2 -= 56;
            const float* row = inp + ((size_t)(b * 3136 + hh2 * 56 + ww2)) * 192;
            float v0 = row[lane], v1 = row[lane + 64], v2 = row[lane + 128];
            float s = v0 + v1 + v2;
            float sq = v0 * v0 + v1 * v1 + v2 * v2;
#pragma unroll
            for (int off = 32; off > 0; off >>= 1) {
                s  += __shfl_down(s, off);
                sq += __shfl_down(sq, off);
            }
            s = __shfl(s, 0); sq = __shfl(sq, 0);
            float mu  = s * (1.0f / 192.0f);
            float var = sq * (1.0f / 192.0f) - mu * mu;
            float inv = rsqrtf(var + 1e-5f);
            XL[t * 200 + lane]       = (bf16_t)((v0 - mu) * inv * g0 + b0);
            XL[t * 200 + lane + 64]  = (bf16_t)((v1 - mu) * inv * g1 + b1);
            XL[t * 200 + lane + 128] = (bf16_t)((v2 - mu) * inv * g2 + b2);
        }
        for (int rr = 49 + h; rr < 64; rr += 6)
            for (int j = lane; j < 192; j += 64)
                XL[rr * 200 + j] = (bf16_t)0.f;
    }
    __syncthreads();   // (1) X staged

    // ---- X A-fragments into registers; then XL is free ----
    bf16x8 xf[4][6];
#pragma unroll
    for (int mt = 0; mt < 4; ++mt)
#pragma unroll
        for (int ks = 0; ks < 6; ++ks)
            xf[mt][ks] = *(const bf16x8*)&XL[(mt * 16 + lr) * 200 + ks * 32 + quad * 8];
    __syncthreads();   // (2) all xf pulled; XL reusable for ctx

    // ---- Phase A1: q,k = X @ Wq,Wk  (64 tok x 64 cols) ----
    floatx4 acc[4][4];
#pragma unroll
    for (int mt = 0; mt < 4; ++mt)
#pragma unroll
        for (int nt = 0; nt < 4; ++nt) acc[mt][nt] = floatx4{0.f,0.f,0.f,0.f};

#pragma unroll
    for (int ks = 0; ks < 6; ++ks) {
        bf16x8 wf0 = *(const bf16x8*)(wcvt + (size_t)(h * 32 + lr) * 192 + ks * 32 + quad * 8);
        bf16x8 wf1 = *(const bf16x8*)(wcvt + (size_t)(h * 32 + 16 + lr) * 192 + ks * 32 + quad * 8);
        bf16x8 wf2 = *(const bf16x8*)(wcvt + (size_t)(192 + h * 32 + lr) * 192 + ks * 32 + quad * 8);
        bf16x8 wf3 = *(const bf16x8*)(wcvt + (size_t)(192 + h * 32 + 16 + lr) * 192 + ks * 32 + quad * 8);
#pragma unroll
        for (int mt = 0; mt < 4; ++mt) {
            acc[mt][0] = MFMA(xf[mt][ks], wf0, acc[mt][0], 0, 0, 0);
            acc[mt][1] = MFMA(xf[mt][ks], wf1, acc[mt][1], 0, 0, 0);
            acc[mt][2] = MFMA(xf[mt][ks], wf2, acc[mt][2], 0, 0, 0);
            acc[mt][3] = MFMA(xf[mt][ks], wf3, acc[mt][3], 0, 0, 0);
        }
    }
    {
        float bq0 = qkv_b[h * 32 + lr],       bq1 = qkv_b[h * 32 + 16 + lr];
        float bk0 = qkv_b[192 + h * 32 + lr], bk1 = qkv_b[192 + h * 32 + 16 + lr];
#pragma unroll
        for (int mt = 0; mt < 4; ++mt)
#pragma unroll
            for (int r = 0; r < 4; ++r) {
                int tok = mt * 16 + quad * 4 + r;
                R[tok * 40 + lr]             = (bf16_t)((acc[mt][0][r] + bq0) * SCALE);
                R[tok * 40 + 16 + lr]        = (bf16_t)((acc[mt][1][r] + bq1) * SCALE);
                R[2560 + tok * 40 + lr]      = (bf16_t)(acc[mt][2][r] + bk0);
                R[2560 + tok * 40 + 16 + lr] = (bf16_t)(acc[mt][3][r] + bk1);
            }
    }

    // ---- QK^T (64x64, K=32) ----
    bf16x8 qf[4], kf[4];
#pragma unroll
    for (int t = 0; t < 4; ++t) {
        qf[t] = *(const bf16x8*)&R[(t * 16 + lr) * 40 + quad * 8];
        kf[t] = *(const bf16x8*)&R[2560 + (t * 16 + lr) * 40 + quad * 8];
    }
    floatx4 s[4][4];
#pragma unroll
    for (int mt = 0; mt < 4; ++mt)
#pragma unroll
        for (int nt = 0; nt < 4; ++nt) s[mt][nt] = floatx4{0.f,0.f,0.f,0.f};
#pragma unroll
    for (int mt = 0; mt < 4; ++mt)
#pragma unroll
        for (int nt = 0; nt < 4; ++nt)
            s[mt][nt] = MFMA(qf[mt], kf[nt], s[mt][nt], 0, 0, 0);

    // bias + mask (C-frag ordered)
    const bf16_t* cb = cb2 + (((size_t)wh * 4) * 64 + lane) * 16;
#pragma unroll
    for (int mt = 0; mt < 4; ++mt) {
        bf16x8 c0 = *(const bf16x8*)(cb + (size_t)mt * 1024);
        bf16x8 c1 = *(const bf16x8*)(cb + (size_t)mt * 1024 + 8);
#pragma unroll
        for (int r = 0; r < 4; ++r) {
            s[mt][0][r] += (float)c0[r];
            s[mt][1][r] += (float)c0[4 + r];
            s[mt][2][r] += (float)c1[r];
            s[mt][3][r] += (float)c1[4 + r];
        }
    }

    // in-register row softmax (row spread over 16 lr lanes x 4 nt regs)
#pragma unroll
    for (int mt = 0; mt < 4; ++mt) {
#pragma unroll
        for (int r = 0; r < 4; ++r) {
            float mx = fmaxf(fmaxf(s[mt][0][r], s[mt][1][r]),
                             fmaxf(s[mt][2][r], s[mt][3][r]));
#pragma unroll
            for (int off = 1; off < 16; off <<= 1)
                mx = fmaxf(mx, __shfl_xor(mx, off));
            float sum = 0.f;
#pragma unroll
            for (int nt = 0; nt < 4; ++nt) {
                float e = __expf(s[mt][nt][r] - mx);
                s[mt][nt][r] = e; sum += e;
            }
#pragma unroll
            for (int off = 1; off < 16; off <<= 1)
                sum += __shfl_xor(sum, off);
            float inv = 1.0f / sum;
#pragma unroll
            for (int nt = 0; nt < 4; ++nt) s[mt][nt][r] *= inv;
        }
    }

    // ---- P -> LDS (overwrites q/k; wave-private), pull A-frags of P ----
#pragma unroll
    for (int mt = 0; mt < 4; ++mt)
#pragma unroll
        for (int nt = 0; nt < 4; ++nt)
#pragma unroll
            for (int r = 0; r < 4; ++r)
                R[(mt * 16 + quad * 4 + r) * 72 + nt * 16 + lr] = (bf16_t)s[mt][nt][r];
    bf16x8 pf[4][2];
#pragma unroll
    for (int mt = 0; mt < 4; ++mt)
#pragma unroll
        for (int kt = 0; kt < 2; ++kt)
            pf[mt][kt] = *(const bf16x8*)&R[(mt * 16 + lr) * 72 + kt * 32 + quad * 8];

    // ---- Phase A2: v = X @ Wv (64 tok x 32 d) ----
    floatx4 va[4][2];
#pragma unroll
    for (int mt = 0; mt < 4; ++mt) { va[mt][0] = floatx4{0.f,0.f,0.f,0.f}; va[mt][1] = floatx4{0.f,0.f,0.f,0.f}; }
#pragma unroll
    for (int ks = 0; ks < 6; ++ks) {
        bf16x8 wv0 = *(const bf16x8*)(wcvt + (size_t)(384 + h * 32 + lr) * 192 + ks * 32 + quad * 8);
        bf16x8 wv1 = *(const bf16x8*)(wcvt + (size_t)(384 + h * 32 + 16 + lr) * 192 + ks * 32 + quad * 8);
#pragma unroll
        for (int mt = 0; mt < 4; ++mt) {
            va[mt][0] = MFMA(xf[mt][ks], wv0, va[mt][0], 0, 0, 0);
            va[mt][1] = MFMA(xf[mt][ks], wv1, va[mt][1], 0, 0, 0);
        }
    }
    // vT into P region rows 0..31 (P frags already in regs; DS in-order)
    {
        float bv0 = qkv_b[384 + h * 32 + lr], bv1 = qkv_b[384 + h * 32 + 16 + lr];
#pragma unroll
        for (int mt = 0; mt < 4; ++mt)
#pragma unroll
            for (int r = 0; r < 4; ++r) {
                int tok = mt * 16 + quad * 4 + r;
                R[lr * 72 + tok]        = (bf16_t)(va[mt][0][r] + bv0);
                R[(16 + lr) * 72 + tok] = (bf16_t)(va[mt][1][r] + bv1);
            }
    }

    // ---- PV (64 x 32, K=64) ----
    bf16x8 vf[2][2];
#pragma unroll
    for (int nt = 0; nt < 2; ++nt)
#pragma unroll
        for (int kt = 0; kt < 2; ++kt)
            vf[nt][kt] = *(const bf16x8*)&R[(nt * 16 + lr) * 72 + kt * 32 + quad * 8];
    floatx4 c[4][2];
#pragma unroll
    for (int mt = 0; mt < 4; ++mt) { c[mt][0] = floatx4{0.f,0.f,0.f,0.f}; c[mt][1] = floatx4{0.f,0.f,0.f,0.f}; }
#pragma unroll
    for (int mt = 0; mt < 4; ++mt)
#pragma unroll
        for (int nt = 0; nt < 2; ++nt) {
            c[mt][nt] = MFMA(pf[mt][0], vf[nt][0], c[mt][nt], 0, 0, 0);
            c[mt][nt] = MFMA(pf[mt][1], vf[nt][1], c[mt][nt], 0, 0, 0);
        }

    // ---- ctx -> XL [64][200] (X long dead; barrier (2) protected it) ----
#pragma unroll
    for (int mt = 0; mt < 4; ++mt)
#pragma unroll
        for (int nt = 0; nt < 2; ++nt)
#pragma unroll
            for (int r = 0; r < 4; ++r)
                XL[(mt * 16 + quad * 4 + r) * 200 + h * 32 + nt * 16 + lr] = (bf16_t)c[mt][nt][r];
    __syncthreads();   // (3) ctx of all heads staged

    // ---- folded lin: out = resid + gelu(ctx @ Wf^T + bf), cols [h*32,h*32+32) ----
    floatx4 pr[4][2];
#pragma unroll
    for (int mt = 0; mt < 4; ++mt) { pr[mt][0] = floatx4{0.f,0.f,0.f,0.f}; pr[mt][1] = floatx4{0.f,0.f,0.f,0.f}; }
#pragma unroll
    for (int ks = 0; ks < 6; ++ks) {
        bf16x8 w0 = *(const bf16x8*)(wfo + (size_t)(h * 32 + lr) * 192 + ks * 32 + quad * 8);
        bf16x8 w1 = *(const bf16x8*)(wfo + (size_t)(h * 32 + 16 + lr) * 192 + ks * 32 + quad * 8);
#pragma unroll
        for (int mt = 0; mt < 4; ++mt) {
            bf16x8 af = *(const bf16x8*)&XL[(mt * 16 + lr) * 200 + ks * 32 + quad * 8];
            pr[mt][0] = MFMA(af, w0, pr[mt][0], 0, 0, 0);
            pr[mt][1] = MFMA(af, w1, pr[mt][1], 0, 0, 0);
        }
    }
    // epilogue: bias + gelu + residual, window-reverse + unshift scatter
    {
        float pb0 = bfb[h * 32 + lr], pb1 = bfb[h * 32 + 16 + lr];
#pragma unroll
        for (int mt = 0; mt < 4; ++mt)
#pragma unroll
            for (int r = 0; r < 4; ++r) {
                int m = mt * 16 + quad * 4 + r;
                if (m < 49) {
                    int ii = m / 7, jj = m - ii * 7;
                    int hh2 = whh * 7 + ii + 3; if (hh2 >= 56) hh2 -= 56;
                    int ww2 = www * 7 + jj + 3; if (ww2 >= 56) ww2 -= 56;
                    size_t base = ((size_t)(b * 3136 + hh2 * 56 + ww2)) * 192 + h * 32;
                    float v0 = pr[mt][0][r] + pb0;
                    float v1 = pr[mt][1][r] + pb1;
                    float gx0 = 0.5f * v0 * (1.0f + erff(v0 * 0.70710678118654752f));
                    float gx1 = 0.5f * v1 * (1.0f + erff(v1 * 0.70710678118654752f));
                    out[base + lr]      = inp[base + lr]      + gx0;
                    out[base + 16 + lr] = inp[base + 16 + lr] + gx1;
                }
            }
    }
}

// ---------------------------------------------------------------------------
extern "C" void kernel_launch(void* const* d_in, const int* in_sizes, int n_in,
                              void* d_out, int out_size, void* d_ws, size_t ws_size,
                              hipStream_t stream)
{
    const float* inp    = (const float*)d_in[0];
    const float* mask   = (const float*)d_in[1];
    const float* g      = (const float*)d_in[2];
    const float* bta    = (const float*)d_in[3];
    const float* qkv_w  = (const float*)d_in[4];
    const float* qkv_b  = (const float*)d_in[5];
    const float* table  = (const float*)d_in[6];
    const int*   rpi    = (const int*)d_in[7];
    const float* proj_w = (const float*)d_in[8];
    const float* proj_b = (const float*)d_in[9];
    const float* lin_w  = (const float*)d_in[10];
    const float* lin_b  = (const float*)d_in[11];
    float* out = (float*)d_out;

    char* ws = (char*)d_ws;
    bf16_t* wcvt = (bf16_t*)(ws);                 // qkv bf16: 221,184 B
    bf16_t* wfo  = wcvt + 110592;                 // folded Wf: 73,728 B
    float*  bfb  = (float*)(ws + 294912);         // folded bias: 768 B
    bf16_t* cb2  = (bf16_t*)(ws + 300032);        // 3,145,728 B (16B aligned)

    prep<<<6768, 256, 0, stream>>>(table, rpi, mask, qkv_w, lin_w, proj_w,
                                   proj_b, lin_b, cb2, wcvt, wfo, bfb);
    fused_window<<<2048, 384, 0, stream>>>(inp, g, bta, wcvt, qkv_b, cb2,
                                           wfo, bfb, out);
}